// Round 2
// baseline (128.345 us; speedup 1.0000x reference)
//
#include <hip/hip_runtime.h>
#include <hip/hip_bf16.h>

#define NSAMP 8192
#define HD 128
#define NC 18
#define SB 8            // samples per block
#define NCOLS 144       // SB*NC = 9 n-tiles of 16
#define KSTR 136        // padded k-stride in shorts (272B rows, 16B-aligned)

typedef __attribute__((ext_vector_type(8))) short bf16x8;
typedef __attribute__((ext_vector_type(4))) float f32x4;
typedef float f2 __attribute__((ext_vector_type(2)));

// Monomial map: 0:1 1:a 2:b 3:c 4:a2 5:ab 6:b2 7:ca 8:cb 9:a3 10:a2b 11:ab2
// 12:b3 13:ca2 14:cb2 15:a4 16:a2b2 17:b4   (a=dx, b=dy, c=dt)

__device__ __forceinline__ unsigned packf2(f2 v) {
    __hip_bfloat162 h = __float22bfloat162_rn(float2{v.x, v.y});
    return *(unsigned*)&h;
}
__device__ __forceinline__ f2 unpk(unsigned r) {
    f2 v;
    v.x = __uint_as_float(r << 16);
    v.y = __uint_as_float(r & 0xffff0000u);
    return v;
}

// R10: branchless fast tanh: 1 - 2*rcp(exp(2x)+1).
// rel err ~1e-6 << bf16 round-trip (4e-3); saturates exactly (rcp(inf)=0).
__device__ __forceinline__ f2 ftanh2(f2 v) {
    const float ex = __expf(v.x * 2.0f);
    const float ey = __expf(v.y * 2.0f);
    const float rx = __builtin_amdgcn_rcpf(ex + 1.0f);
    const float ry = __builtin_amdgcn_rcpf(ey + 1.0f);
    f2 r;
    r.x = 1.0f - (rx + rx);
    r.y = 1.0f - (ry + ry);
    return r;
}

// tanh jet: out = y + s*p + P*(t2 + t3*p + t4*P), P = p^2 (18-monomial trunc)
__device__ __forceinline__ void tanh_jet2(const f2* __restrict__ f,
                                          f2* __restrict__ out) {
    const f2 y = ftanh2(f[0]);
    const f2 one = {1.0f, 1.0f};
    const f2 s  = one - y*y;
    const f2 t2 = -y*s;
    const f2 t3 = s*(y*y - 0.3333333333333333f);
    const f2 t4 = y*s*(one + one - 3.0f*y*y) * 0.3333333333333333f;
    const f2 tp1 = f[1]+f[1], tp2 = f[2]+f[2], tp3 = f[3]+f[3], tp4 = f[4]+f[4];
    f2 P[18];
    P[4]  = f[1]*f[1];
    P[5]  = tp1*f[2];
    P[6]  = f[2]*f[2];
    P[7]  = tp1*f[3];
    P[8]  = tp2*f[3];
    P[9]  = tp1*f[4];
    P[10] = tp1*f[5]  + tp2*f[4];
    P[11] = tp1*f[6]  + tp2*f[5];
    P[12] = tp2*f[6];
    P[13] = tp1*f[7]  + tp3*f[4];
    P[14] = tp2*f[8]  + tp3*f[6];
    P[15] = tp1*f[9]  + f[4]*f[4];
    P[16] = tp1*f[11] + tp2*f[10] + tp4*f[6] + f[5]*f[5];
    P[17] = tp2*f[12] + f[6]*f[6];
    f2 q[18];
    q[0] = t2;
    q[1] = t3*f[1];  q[2] = t3*f[2];  q[3] = t3*f[3];
#pragma unroll
    for (int m = 4; m <= 17; ++m) q[m] = t3*f[m] + t4*P[m];
    out[0] = y;
    out[1] = s*f[1];  out[2] = s*f[2];  out[3] = s*f[3];
    out[4] = s*f[4]  + P[4]*q[0];
    out[5] = s*f[5]  + P[5]*q[0];
    out[6] = s*f[6]  + P[6]*q[0];
    out[7] = s*f[7]  + P[7]*q[0];
    out[8] = s*f[8]  + P[8]*q[0];
    out[9]  = s*f[9]  + P[9]*q[0]  + P[4]*q[1];
    out[10] = s*f[10] + P[10]*q[0] + P[5]*q[1] + P[4]*q[2];
    out[11] = s*f[11] + P[11]*q[0] + P[6]*q[1] + P[5]*q[2];
    out[12] = s*f[12] + P[12]*q[0] + P[6]*q[2];
    out[13] = s*f[13] + P[13]*q[0] + P[7]*q[1] + P[4]*q[3];
    out[14] = s*f[14] + P[14]*q[0] + P[8]*q[2] + P[6]*q[3];
    out[15] = s*f[15] + P[15]*q[0] + P[9]*q[1] + P[4]*q[4];
    out[16] = s*f[16] + P[16]*q[0] + P[11]*q[1] + P[10]*q[2]
            + P[4]*q[6] + P[6]*q[4] + P[5]*q[5];
    out[17] = s*f[17] + P[17]*q[0] + P[12]*q[2] + P[6]*q[6];
}

// Layer-1 jet: input jet is LINEAR (p1,p2,p3 only) -> fully sparse
__device__ __forceinline__ void tanh_jet_lin2(f2 f0, f2 p1, f2 p2, f2 p3,
                                              f2* __restrict__ out) {
    const f2 y = ftanh2(f0);
    const f2 one = {1.0f, 1.0f};
    const f2 s  = one - y*y;
    const f2 t2 = -y*s;
    const f2 t3 = s*(y*y - 0.3333333333333333f);
    const f2 t4 = y*s*(one + one - 3.0f*y*y) * 0.3333333333333333f;
    const f2 tp1 = p1+p1, tp2 = p2+p2;
    const f2 P4 = p1*p1, P5 = tp1*p2, P6 = p2*p2, P7 = tp1*p3, P8 = tp2*p3;
    const f2 q0 = t2;
    const f2 q1 = t3*p1, q2 = t3*p2, q3 = t3*p3;
    const f2 q4 = t4*P4, q5 = t4*P5, q6 = t4*P6;
    out[0] = y;
    out[1] = s*p1;  out[2] = s*p2;  out[3] = s*p3;
    out[4] = P4*q0; out[5] = P5*q0; out[6] = P6*q0;
    out[7] = P7*q0; out[8] = P8*q0;
    out[9]  = P4*q1;
    out[10] = P4*q2 + P5*q1;
    out[11] = P5*q2 + P6*q1;
    out[12] = P6*q2;
    out[13] = P4*q3 + P7*q1;
    out[14] = P6*q3 + P8*q2;
    out[15] = P4*q4;
    out[16] = P4*q6 + P6*q4 + P5*q5;
    out[17] = P6*q6;
}

// NOTES (measured across R4-R11):
// - __launch_bounds__ 2nd arg acts as a residency cap: (512,2) -> ~20% occ
//   (R6,R8 regressions). (512,8) pins hard 64-VGPR cap (8 waves/SIMD).
// - GEMM tiling wave=(1 m-tile x 9 n-tiles) beats 2x5 m-grouping by ~13us
//   (R5/R9 both regressed; bank conflicts 10x higher there).
// - R10: transpose_w dispatch eliminated; A gathered from global W (stride
//   512B, line-efficient: 16 lanes x 4B fill each 64B line; L2-hot).
//   libm tanhf -> ftanh2 everywhere. Net ~neutral-to-positive (machine
//   noise +-4% masked it; fills 40->43.5us between runs).
// - R11: A-pack moved INSIDE the ks loop: first MFMA now waits on only 8
//   gather loads (not all 32); remaining 24 stay in flight under ks=0's
//   nt-loop. Also shrinks Af liveness (was 16 VGPR across the whole loop).
//   L4: 4 accumulators (serial 128-fma chain -> 4x32, ~380cy shorter).
// - LDS floor estimate: ~864KB/block total traffic -> ~13us at 69TB/s;
//   GEMM B-rereads (288KB/layer) are 2/3 of it. Next structural lever
//   would be 32x32 MFMA (2x LDS intensity) but needs full-kernel XOR
//   swizzle + 144-col tail handling; ~4us EV at high risk.
__global__ __launch_bounds__(512, 8)
void hydro_main(const float* __restrict__ x,
                const float* __restrict__ W1, const float* __restrict__ b1,
                const float* __restrict__ W2, const float* __restrict__ b2,
                const float* __restrict__ W3, const float* __restrict__ b3,
                const float* __restrict__ W4, const float* __restrict__ nu_p,
                float* __restrict__ out) {
    __shared__ __align__(16) unsigned short Hl[NCOLS * KSTR];  // jets/preacts, bf16
    __shared__ float psis[NCOLS];

    const int tid = threadIdx.x;
    const int wv  = tid >> 6;
    const int ln  = tid & 63;
    const int s0  = blockIdx.x * SB;
    const int s   = tid >> 6;          // sample slot 0..7
    const int jp  = tid & 63;          // unit pair 0..63

    // ---- Layer 1: 512 unit-pairs, sparse float2 jets ----
    {
        const float xs = x[3 * (s0 + s) + 0];
        const float ys = x[3 * (s0 + s) + 1];
        const float ts = x[3 * (s0 + s) + 2];
        const int j0 = 2 * jp;
        const f2 wx = *(const f2*)&W1[j0];
        const f2 wy = *(const f2*)&W1[HD + j0];
        const f2 wt = *(const f2*)&W1[2 * HD + j0];
        const f2 bb = *(const f2*)&b1[j0];
        f2 h[NC];
        const f2 fc = wx * xs + wy * ys + wt * ts + bb;
        tanh_jet_lin2(fc, wx, wy, wt, h);
#pragma unroll
        for (int c = 0; c < NC; ++c)
            *(unsigned*)&Hl[(s * NC + c) * KSTR + j0] = packf2(h[c]);
    }
    __syncthreads();

    // ---- Layers 2,3: MFMA GEMM (A gathered from global W, k-strided) + tanh ----
    const int lr   = ln & 15;
    const int koff = (ln >> 4) * 8;

#pragma unroll 1
    for (int L = 0; L < 2; ++L) {
        const float* __restrict__ Wg = L ? W3 : W2;
        f32x4 acc[9];
#pragma unroll
        for (int nt = 0; nt < 9; ++nt) acc[nt] = (f32x4)0.0f;
        // A-frag gather+pack per ks INSIDE the loop: first MFMA waits on
        // only its own 8 loads; later ks' loads overlap ks=0's MFMAs.
#pragma unroll
        for (int ks = 0; ks < 4; ++ks) {
            const float* wp = &Wg[(ks * 32 + koff) * HD + (wv * 16 + lr)];
            const unsigned r0 = packf2(f2{wp[0 * HD], wp[1 * HD]});
            const unsigned r1 = packf2(f2{wp[2 * HD], wp[3 * HD]});
            const unsigned r2 = packf2(f2{wp[4 * HD], wp[5 * HD]});
            const unsigned r3 = packf2(f2{wp[6 * HD], wp[7 * HD]});
            const uint4 q{r0, r1, r2, r3};
            const bf16x8 Af = *(const bf16x8*)&q;
#pragma unroll
            for (int nt = 0; nt < 9; ++nt) {
                const bf16x8 Bf = *(const bf16x8*)&Hl[(nt * 16 + lr) * KSTR + ks * 32 + koff];
                acc[nt] = __builtin_amdgcn_mfma_f32_16x16x32_bf16(Af, Bf, acc[nt], 0, 0, 0);
            }
        }
        __syncthreads();
        // writeback pre-activations: C[m][n] -> Hl[n][m], bf16
#pragma unroll
        for (int nt = 0; nt < 9; ++nt) {
            const int n = nt * 16 + lr;
            const int m = wv * 16 + (ln >> 4) * 4;
            uint2 w;
            w.x = packf2(f2{acc[nt].x, acc[nt].y});
            w.y = packf2(f2{acc[nt].z, acc[nt].w});
            *(uint2*)&Hl[n * KSTR + m] = w;
        }
        __syncthreads();
        // tanh phase: ALL 512 threads, one f2-jet each, b32 LDS ops
        // (wave-uniform row + lane-contiguous dwords -> conflict-free)
        {
            const float* bL = L ? b3 : b2;
            const int j0 = 2 * jp;
            f2 fa[NC], ha[NC];
#pragma unroll
            for (int c = 0; c < NC; ++c)
                fa[c] = unpk(*(const unsigned*)&Hl[(s * NC + c) * KSTR + j0]);
            fa[0] += *(const f2*)&bL[j0];
            tanh_jet2(fa, ha);
#pragma unroll
            for (int c = 0; c < NC; ++c)
                *(unsigned*)&Hl[(s * NC + c) * KSTR + j0] = packf2(ha[c]);
        }
        __syncthreads();
    }

    // ---- Layer 4: psi jet coefs = W4 . h3 (4 accumulators: chain 128->32) ----
    if (tid < NCOLS) {
        float a0 = 0.0f, a1 = 0.0f, a2 = 0.0f, a3 = 0.0f;
#pragma unroll
        for (int kk = 0; kk < 16; kk += 4) {
            const uint4 q0 = *(const uint4*)&Hl[tid * KSTR + (kk + 0) * 8];
            const uint4 q1 = *(const uint4*)&Hl[tid * KSTR + (kk + 1) * 8];
            const uint4 q2 = *(const uint4*)&Hl[tid * KSTR + (kk + 2) * 8];
            const uint4 q3 = *(const uint4*)&Hl[tid * KSTR + (kk + 3) * 8];
            const int k = kk * 8;
            f2 e;
            e = unpk(q0.x); a0 = fmaf(e.x, W4[k+ 0], a0); a0 = fmaf(e.y, W4[k+ 1], a0);
            e = unpk(q0.y); a0 = fmaf(e.x, W4[k+ 2], a0); a0 = fmaf(e.y, W4[k+ 3], a0);
            e = unpk(q0.z); a0 = fmaf(e.x, W4[k+ 4], a0); a0 = fmaf(e.y, W4[k+ 5], a0);
            e = unpk(q0.w); a0 = fmaf(e.x, W4[k+ 6], a0); a0 = fmaf(e.y, W4[k+ 7], a0);
            e = unpk(q1.x); a1 = fmaf(e.x, W4[k+ 8], a1); a1 = fmaf(e.y, W4[k+ 9], a1);
            e = unpk(q1.y); a1 = fmaf(e.x, W4[k+10], a1); a1 = fmaf(e.y, W4[k+11], a1);
            e = unpk(q1.z); a1 = fmaf(e.x, W4[k+12], a1); a1 = fmaf(e.y, W4[k+13], a1);
            e = unpk(q1.w); a1 = fmaf(e.x, W4[k+14], a1); a1 = fmaf(e.y, W4[k+15], a1);
            e = unpk(q2.x); a2 = fmaf(e.x, W4[k+16], a2); a2 = fmaf(e.y, W4[k+17], a2);
            e = unpk(q2.y); a2 = fmaf(e.x, W4[k+18], a2); a2 = fmaf(e.y, W4[k+19], a2);
            e = unpk(q2.z); a2 = fmaf(e.x, W4[k+20], a2); a2 = fmaf(e.y, W4[k+21], a2);
            e = unpk(q2.w); a2 = fmaf(e.x, W4[k+22], a2); a2 = fmaf(e.y, W4[k+23], a2);
            e = unpk(q3.x); a3 = fmaf(e.x, W4[k+24], a3); a3 = fmaf(e.y, W4[k+25], a3);
            e = unpk(q3.y); a3 = fmaf(e.x, W4[k+26], a3); a3 = fmaf(e.y, W4[k+27], a3);
            e = unpk(q3.z); a3 = fmaf(e.x, W4[k+28], a3); a3 = fmaf(e.y, W4[k+29], a3);
            e = unpk(q3.w); a3 = fmaf(e.x, W4[k+30], a3); a3 = fmaf(e.y, W4[k+31], a3);
        }
        psis[tid] = (a0 + a1) + (a2 + a3);
    }
    __syncthreads();

    if (tid < SB) {
        const float* p = &psis[tid * NC];
        const float nu = nu_p[0];
        const float u  = p[2];
        const float v  = -p[1];
        const float wx = -(6.0f * p[9]  + 2.0f * p[11]);
        const float wy = -(2.0f * p[10] + 6.0f * p[12]);
        const float wt = -(2.0f * p[13] + 2.0f * p[14]);
        const float lapw = -(24.0f * p[15] + 8.0f * p[16] + 24.0f * p[17]);
        const float nse  = wt + wx * u + wy * v - nu * lapw;
        const int gi = s0 + tid;
        out[2 * gi]         = u;
        out[2 * gi + 1]     = v;
        out[2 * NSAMP + gi] = nse;
    }
}

extern "C" void kernel_launch(void* const* d_in, const int* in_sizes, int n_in,
                              void* d_out, int out_size, void* d_ws, size_t ws_size,
                              hipStream_t stream) {
    const float* x  = (const float*)d_in[0];
    const float* W1 = (const float*)d_in[1];
    const float* b1 = (const float*)d_in[2];
    const float* W2 = (const float*)d_in[3];
    const float* b2 = (const float*)d_in[4];
    const float* W3 = (const float*)d_in[5];
    const float* b3 = (const float*)d_in[6];
    const float* W4 = (const float*)d_in[7];
    const float* nu = (const float*)d_in[9];
    float* out = (float*)d_out;

    hipLaunchKernelGGL(hydro_main, dim3(NSAMP / SB), dim3(512), 0, stream,
                       x, W1, b1, W2, b2, W3, b3, W4, nu, out);
}

// Round 3
// 94.626 us; speedup vs baseline: 1.3563x; 1.3563x over previous
//
#include <hip/hip_runtime.h>
#include <hip/hip_bf16.h>

#define NSAMP 8192
#define HD 128
#define NC 18
#define SB 8            // samples per block
#define NCOLS 144       // SB*NC = 9 n-tiles of 16
#define KSTR 136        // padded k-stride in shorts (272B rows, 16B-aligned)

typedef __attribute__((ext_vector_type(8))) short bf16x8;
typedef __attribute__((ext_vector_type(4))) float f32x4;
typedef float f2 __attribute__((ext_vector_type(2)));

// Monomial map: 0:1 1:a 2:b 3:c 4:a2 5:ab 6:b2 7:ca 8:cb 9:a3 10:a2b 11:ab2
// 12:b3 13:ca2 14:cb2 15:a4 16:a2b2 17:b4   (a=dx, b=dy, c=dt)

__device__ __forceinline__ unsigned packf2(f2 v) {
    __hip_bfloat162 h = __float22bfloat162_rn(float2{v.x, v.y});
    return *(unsigned*)&h;
}
__device__ __forceinline__ f2 unpk(unsigned r) {
    f2 v;
    v.x = __uint_as_float(r << 16);
    v.y = __uint_as_float(r & 0xffff0000u);
    return v;
}

// R10: branchless fast tanh: 1 - 2*rcp(exp(2x)+1).
// rel err ~1e-6 << bf16 round-trip (4e-3); saturates exactly (rcp(inf)=0).
__device__ __forceinline__ f2 ftanh2(f2 v) {
    const float ex = __expf(v.x * 2.0f);
    const float ey = __expf(v.y * 2.0f);
    const float rx = __builtin_amdgcn_rcpf(ex + 1.0f);
    const float ry = __builtin_amdgcn_rcpf(ey + 1.0f);
    f2 r;
    r.x = 1.0f - (rx + rx);
    r.y = 1.0f - (ry + ry);
    return r;
}

// tanh jet: out = y + s*p + P*(t2 + t3*p + t4*P), P = p^2 (18-monomial trunc)
__device__ __forceinline__ void tanh_jet2(const f2* __restrict__ f,
                                          f2* __restrict__ out) {
    const f2 y = ftanh2(f[0]);
    const f2 one = {1.0f, 1.0f};
    const f2 s  = one - y*y;
    const f2 t2 = -y*s;
    const f2 t3 = s*(y*y - 0.3333333333333333f);
    const f2 t4 = y*s*(one + one - 3.0f*y*y) * 0.3333333333333333f;
    const f2 tp1 = f[1]+f[1], tp2 = f[2]+f[2], tp3 = f[3]+f[3], tp4 = f[4]+f[4];
    f2 P[18];
    P[4]  = f[1]*f[1];
    P[5]  = tp1*f[2];
    P[6]  = f[2]*f[2];
    P[7]  = tp1*f[3];
    P[8]  = tp2*f[3];
    P[9]  = tp1*f[4];
    P[10] = tp1*f[5]  + tp2*f[4];
    P[11] = tp1*f[6]  + tp2*f[5];
    P[12] = tp2*f[6];
    P[13] = tp1*f[7]  + tp3*f[4];
    P[14] = tp2*f[8]  + tp3*f[6];
    P[15] = tp1*f[9]  + f[4]*f[4];
    P[16] = tp1*f[11] + tp2*f[10] + tp4*f[6] + f[5]*f[5];
    P[17] = tp2*f[12] + f[6]*f[6];
    f2 q[18];
    q[0] = t2;
    q[1] = t3*f[1];  q[2] = t3*f[2];  q[3] = t3*f[3];
#pragma unroll
    for (int m = 4; m <= 17; ++m) q[m] = t3*f[m] + t4*P[m];
    out[0] = y;
    out[1] = s*f[1];  out[2] = s*f[2];  out[3] = s*f[3];
    out[4] = s*f[4]  + P[4]*q[0];
    out[5] = s*f[5]  + P[5]*q[0];
    out[6] = s*f[6]  + P[6]*q[0];
    out[7] = s*f[7]  + P[7]*q[0];
    out[8] = s*f[8]  + P[8]*q[0];
    out[9]  = s*f[9]  + P[9]*q[0]  + P[4]*q[1];
    out[10] = s*f[10] + P[10]*q[0] + P[5]*q[1] + P[4]*q[2];
    out[11] = s*f[11] + P[11]*q[0] + P[6]*q[1] + P[5]*q[2];
    out[12] = s*f[12] + P[12]*q[0] + P[6]*q[2];
    out[13] = s*f[13] + P[13]*q[0] + P[7]*q[1] + P[4]*q[3];
    out[14] = s*f[14] + P[14]*q[0] + P[8]*q[2] + P[6]*q[3];
    out[15] = s*f[15] + P[15]*q[0] + P[9]*q[1] + P[4]*q[4];
    out[16] = s*f[16] + P[16]*q[0] + P[11]*q[1] + P[10]*q[2]
            + P[4]*q[6] + P[6]*q[4] + P[5]*q[5];
    out[17] = s*f[17] + P[17]*q[0] + P[12]*q[2] + P[6]*q[6];
}

// Layer-1 jet: input jet is LINEAR (p1,p2,p3 only) -> fully sparse
__device__ __forceinline__ void tanh_jet_lin2(f2 f0, f2 p1, f2 p2, f2 p3,
                                              f2* __restrict__ out) {
    const f2 y = ftanh2(f0);
    const f2 one = {1.0f, 1.0f};
    const f2 s  = one - y*y;
    const f2 t2 = -y*s;
    const f2 t3 = s*(y*y - 0.3333333333333333f);
    const f2 t4 = y*s*(one + one - 3.0f*y*y) * 0.3333333333333333f;
    const f2 tp1 = p1+p1, tp2 = p2+p2;
    const f2 P4 = p1*p1, P5 = tp1*p2, P6 = p2*p2, P7 = tp1*p3, P8 = tp2*p3;
    const f2 q0 = t2;
    const f2 q1 = t3*p1, q2 = t3*p2, q3 = t3*p3;
    const f2 q4 = t4*P4, q5 = t4*P5, q6 = t4*P6;
    out[0] = y;
    out[1] = s*p1;  out[2] = s*p2;  out[3] = s*p3;
    out[4] = P4*q0; out[5] = P5*q0; out[6] = P6*q0;
    out[7] = P7*q0; out[8] = P8*q0;
    out[9]  = P4*q1;
    out[10] = P4*q2 + P5*q1;
    out[11] = P5*q2 + P6*q1;
    out[12] = P6*q2;
    out[13] = P4*q3 + P7*q1;
    out[14] = P6*q3 + P8*q2;
    out[15] = P4*q4;
    out[16] = P4*q6 + P6*q4 + P5*q5;
    out[17] = P6*q6;
}

// NOTES (measured across R4-R12):
// - LAUNCH_BOUNDS SEMANTICS (R12 discovery, counter-verified): the 2nd arg
//   behaves as CUDA-style min-BLOCKS-per-CU here, NOT waves/EU.
//   (512,8) -> 64 waves/CU target -> 16 waves/SIMD -> 32-VGPR cap ->
//   acc[9] spilled to scratch: VGPR_Count=32, 218MB scratch HBM traffic
//   per dispatch, hydro_main 65us (R2 counters). (512,4) -> 8 waves/SIMD
//   -> 64-VGPR cap, VGPR=64 measured, no spill. DO NOT raise the 2nd arg.
// - VGPR=64 is load-bearing: 8 waves/SIMD x 4 blocks/CU needs <=64.
// - GEMM tiling wave=(1 m-tile x 9 n-tiles) beats 2x5 m-grouping by ~13us
//   (R5/R9 both regressed; bank conflicts 10x higher there).
// - R10: transpose_w dispatch eliminated; A gathered from global W (stride
//   512B, line-efficient: 16 lanes x 4B fill each 64B line; L2-hot).
//   libm tanhf -> ftanh2 everywhere.
// - R11 REGRESSION (reverted): A-pack inside the ks loop extended load
//   liveness across acc -> spill hell. Gather must stay BEFORE acc init
//   (R0's liveness order: loads retire into 16 VGPR of Af before acc
//   comes live).
// - L4: 4 accumulators (serial 128-fma chain -> 4x32, ~380cy shorter).
// - LDS floor estimate: ~864KB/block total traffic -> ~13us at 69TB/s;
//   GEMM B-rereads (288KB/layer) are 2/3 of it.
__global__ __launch_bounds__(512, 4)
void hydro_main(const float* __restrict__ x,
                const float* __restrict__ W1, const float* __restrict__ b1,
                const float* __restrict__ W2, const float* __restrict__ b2,
                const float* __restrict__ W3, const float* __restrict__ b3,
                const float* __restrict__ W4, const float* __restrict__ nu_p,
                float* __restrict__ out) {
    __shared__ __align__(16) unsigned short Hl[NCOLS * KSTR];  // jets/preacts, bf16
    __shared__ float psis[NCOLS];

    const int tid = threadIdx.x;
    const int wv  = tid >> 6;
    const int ln  = tid & 63;
    const int s0  = blockIdx.x * SB;
    const int s   = tid >> 6;          // sample slot 0..7
    const int jp  = tid & 63;          // unit pair 0..63

    // ---- Layer 1: 512 unit-pairs, sparse float2 jets ----
    {
        const float xs = x[3 * (s0 + s) + 0];
        const float ys = x[3 * (s0 + s) + 1];
        const float ts = x[3 * (s0 + s) + 2];
        const int j0 = 2 * jp;
        const f2 wx = *(const f2*)&W1[j0];
        const f2 wy = *(const f2*)&W1[HD + j0];
        const f2 wt = *(const f2*)&W1[2 * HD + j0];
        const f2 bb = *(const f2*)&b1[j0];
        f2 h[NC];
        const f2 fc = wx * xs + wy * ys + wt * ts + bb;
        tanh_jet_lin2(fc, wx, wy, wt, h);
#pragma unroll
        for (int c = 0; c < NC; ++c)
            *(unsigned*)&Hl[(s * NC + c) * KSTR + j0] = packf2(h[c]);
    }
    __syncthreads();

    // ---- Layers 2,3: MFMA GEMM (A gathered from global W, k-strided) + tanh ----
    const int lr   = ln & 15;
    const int koff = (ln >> 4) * 8;

#pragma unroll 1
    for (int L = 0; L < 2; ++L) {
        const float* __restrict__ Wg = L ? W3 : W2;
        // A-frag gather BEFORE acc init (proven liveness order): 32 strided
        // fp32 loads retire into 16 VGPR of packed Af; only then acc{36}
        // comes live. Peak pressure stays under the 64-VGPR cap.
        bf16x8 Af[4];
#pragma unroll
        for (int ks = 0; ks < 4; ++ks) {
            const float* wp = &Wg[(ks * 32 + koff) * HD + (wv * 16 + lr)];
            const unsigned r0 = packf2(f2{wp[0 * HD], wp[1 * HD]});
            const unsigned r1 = packf2(f2{wp[2 * HD], wp[3 * HD]});
            const unsigned r2 = packf2(f2{wp[4 * HD], wp[5 * HD]});
            const unsigned r3 = packf2(f2{wp[6 * HD], wp[7 * HD]});
            const uint4 q{r0, r1, r2, r3};
            Af[ks] = *(const bf16x8*)&q;
        }
        f32x4 acc[9];
#pragma unroll
        for (int nt = 0; nt < 9; ++nt) acc[nt] = (f32x4)0.0f;
#pragma unroll
        for (int ks = 0; ks < 4; ++ks) {
#pragma unroll
            for (int nt = 0; nt < 9; ++nt) {
                const bf16x8 Bf = *(const bf16x8*)&Hl[(nt * 16 + lr) * KSTR + ks * 32 + koff];
                acc[nt] = __builtin_amdgcn_mfma_f32_16x16x32_bf16(Af[ks], Bf, acc[nt], 0, 0, 0);
            }
        }
        __syncthreads();
        // writeback pre-activations: C[m][n] -> Hl[n][m], bf16
#pragma unroll
        for (int nt = 0; nt < 9; ++nt) {
            const int n = nt * 16 + lr;
            const int m = wv * 16 + (ln >> 4) * 4;
            uint2 w;
            w.x = packf2(f2{acc[nt].x, acc[nt].y});
            w.y = packf2(f2{acc[nt].z, acc[nt].w});
            *(uint2*)&Hl[n * KSTR + m] = w;
        }
        __syncthreads();
        // tanh phase: ALL 512 threads, one f2-jet each, b32 LDS ops
        // (wave-uniform row + lane-contiguous dwords -> conflict-free)
        {
            const float* bL = L ? b3 : b2;
            const int j0 = 2 * jp;
            f2 fa[NC], ha[NC];
#pragma unroll
            for (int c = 0; c < NC; ++c)
                fa[c] = unpk(*(const unsigned*)&Hl[(s * NC + c) * KSTR + j0]);
            fa[0] += *(const f2*)&bL[j0];
            tanh_jet2(fa, ha);
#pragma unroll
            for (int c = 0; c < NC; ++c)
                *(unsigned*)&Hl[(s * NC + c) * KSTR + j0] = packf2(ha[c]);
        }
        __syncthreads();
    }

    // ---- Layer 4: psi jet coefs = W4 . h3 (4 accumulators: chain 128->32) ----
    if (tid < NCOLS) {
        float a0 = 0.0f, a1 = 0.0f, a2 = 0.0f, a3 = 0.0f;
#pragma unroll
        for (int kk = 0; kk < 16; kk += 4) {
            const uint4 q0 = *(const uint4*)&Hl[tid * KSTR + (kk + 0) * 8];
            const uint4 q1 = *(const uint4*)&Hl[tid * KSTR + (kk + 1) * 8];
            const uint4 q2 = *(const uint4*)&Hl[tid * KSTR + (kk + 2) * 8];
            const uint4 q3 = *(const uint4*)&Hl[tid * KSTR + (kk + 3) * 8];
            const int k = kk * 8;
            f2 e;
            e = unpk(q0.x); a0 = fmaf(e.x, W4[k+ 0], a0); a0 = fmaf(e.y, W4[k+ 1], a0);
            e = unpk(q0.y); a0 = fmaf(e.x, W4[k+ 2], a0); a0 = fmaf(e.y, W4[k+ 3], a0);
            e = unpk(q0.z); a0 = fmaf(e.x, W4[k+ 4], a0); a0 = fmaf(e.y, W4[k+ 5], a0);
            e = unpk(q0.w); a0 = fmaf(e.x, W4[k+ 6], a0); a0 = fmaf(e.y, W4[k+ 7], a0);
            e = unpk(q1.x); a1 = fmaf(e.x, W4[k+ 8], a1); a1 = fmaf(e.y, W4[k+ 9], a1);
            e = unpk(q1.y); a1 = fmaf(e.x, W4[k+10], a1); a1 = fmaf(e.y, W4[k+11], a1);
            e = unpk(q1.z); a1 = fmaf(e.x, W4[k+12], a1); a1 = fmaf(e.y, W4[k+13], a1);
            e = unpk(q1.w); a1 = fmaf(e.x, W4[k+14], a1); a1 = fmaf(e.y, W4[k+15], a1);
            e = unpk(q2.x); a2 = fmaf(e.x, W4[k+16], a2); a2 = fmaf(e.y, W4[k+17], a2);
            e = unpk(q2.y); a2 = fmaf(e.x, W4[k+18], a2); a2 = fmaf(e.y, W4[k+19], a2);
            e = unpk(q2.z); a2 = fmaf(e.x, W4[k+20], a2); a2 = fmaf(e.y, W4[k+21], a2);
            e = unpk(q2.w); a2 = fmaf(e.x, W4[k+22], a2); a2 = fmaf(e.y, W4[k+23], a2);
            e = unpk(q3.x); a3 = fmaf(e.x, W4[k+24], a3); a3 = fmaf(e.y, W4[k+25], a3);
            e = unpk(q3.y); a3 = fmaf(e.x, W4[k+26], a3); a3 = fmaf(e.y, W4[k+27], a3);
            e = unpk(q3.z); a3 = fmaf(e.x, W4[k+28], a3); a3 = fmaf(e.y, W4[k+29], a3);
            e = unpk(q3.w); a3 = fmaf(e.x, W4[k+30], a3); a3 = fmaf(e.y, W4[k+31], a3);
        }
        psis[tid] = (a0 + a1) + (a2 + a3);
    }
    __syncthreads();

    if (tid < SB) {
        const float* p = &psis[tid * NC];
        const float nu = nu_p[0];
        const float u  = p[2];
        const float v  = -p[1];
        const float wx = -(6.0f * p[9]  + 2.0f * p[11]);
        const float wy = -(2.0f * p[10] + 6.0f * p[12]);
        const float wt = -(2.0f * p[13] + 2.0f * p[14]);
        const float lapw = -(24.0f * p[15] + 8.0f * p[16] + 24.0f * p[17]);
        const float nse  = wt + wx * u + wy * v - nu * lapw;
        const int gi = s0 + tid;
        out[2 * gi]         = u;
        out[2 * gi + 1]     = v;
        out[2 * NSAMP + gi] = nse;
    }
}

extern "C" void kernel_launch(void* const* d_in, const int* in_sizes, int n_in,
                              void* d_out, int out_size, void* d_ws, size_t ws_size,
                              hipStream_t stream) {
    const float* x  = (const float*)d_in[0];
    const float* W1 = (const float*)d_in[1];
    const float* b1 = (const float*)d_in[2];
    const float* W2 = (const float*)d_in[3];
    const float* b2 = (const float*)d_in[4];
    const float* W3 = (const float*)d_in[5];
    const float* b3 = (const float*)d_in[6];
    const float* W4 = (const float*)d_in[7];
    const float* nu = (const float*)d_in[9];
    float* out = (float*)d_out;

    hipLaunchKernelGGL(hydro_main, dim3(NSAMP / SB), dim3(512), 0, stream,
                       x, W1, b1, W2, b2, W3, b3, W4, nu, out);
}